// Round 3
// baseline (121.190 us; speedup 1.0000x reference)
//
#include <hip/hip_runtime.h>
#include <math.h>

// Problem constants (reference: N=250000, D=16, L=6, K=64, gamma=0.1)
#define NPOINTS 250000
#define LL 6
#define DD 16
#define KK 64
#define TPB 384            // 6 waves; wave w handles layer w for the block's points
#define PTS_PER_BLOCK 128  // R15: halved -> 1954 blocks; occupancy was GRID-limited
#define NTILES (PTS_PER_BLOCK / 16)

// LDS layout (byte offsets):
//  sxu:  point p at p*80,    [0, 10240)
//  smc:  SMC_OFF, 6*128*4 B  [10240, 13312)
#define SMC_OFF (PTS_PER_BLOCK * 80)
#define LDS_BYTES (SMC_OFF + LL * PTS_PER_BLOCK * 4)

// d_ws layout (bytes):
//  WS_MU: column (l*64+k) as 64 B = 32 B bf16-hi + 32 B bf16-lo, pre-scaled -1/2
//  WS_AV: av[l*64+k] = C_AA*alpha - W0
//  WS_WV: exp(-ws^2) per layer
#define WS_MU 0
#define WS_AV 24576
#define WS_WV 26112

typedef __attribute__((ext_vector_type(8))) short bf16x8;
typedef __attribute__((ext_vector_type(4))) float f32x4;
typedef __attribute__((ext_vector_type(2))) float f32x2;

#if __has_builtin(__builtin_amdgcn_exp2f)
#define EXP2F(x) __builtin_amdgcn_exp2f(x)
#else
#define EXP2F(x) exp2f(x)
#endif
#if __has_builtin(__builtin_amdgcn_logf)
#define LOG2F(x) __builtin_amdgcn_logf(x)
#else
#define LOG2F(x) log2f(x)
#endif

#define C_AA   (-14.426950408889634f)   // -10 * log2(e)
#define C_GLN2 (0.06931471805599453f)   // gamma * ln(2)

// Fused distance->log2 term: with mu pre-scaled by -1/2, MFMA emits x' = -ip/2
// and t2 = (aa - w0) + x'*Vt(x').  Vt = degree-5 poly (error budget: |err(F)|
// <= ~2.6e-4).  Estrin evaluation.
#define W0  17.797117f
#define VT0 (-45.300328f)
#define VT1 (-28.559404f)
#define VT2 (-27.844414f)
#define VT3 (-30.475230f)
#define VT4 (-36.246253f)
#define VT5 (-27.207285f)

__device__ __forceinline__ f32x2 s2(float v) { f32x2 r; r.x = v; r.y = v; return r; }

__device__ __forceinline__ ushort bf16_rne(float f) {
  unsigned u = __float_as_uint(f);
  unsigned r = u + 0x7FFFu + ((u >> 16) & 1u);
  return (ushort)(r >> 16);
}

// packed pair: exp2( (aa-w0) + xp*Vt(xp) ), xp = -ip/2 from MFMA.  Estrin:
// Vt = P01 + xp^2*(P23 + xp^2*P45), Pij = VTi + VTj*xp.
__device__ __forceinline__ f32x2 term2(f32x2 xp, f32x2 aaw) {
  f32x2 x2  = xp * xp;
  f32x2 p01 = __builtin_elementwise_fma(s2(VT1), xp, s2(VT0));
  f32x2 p23 = __builtin_elementwise_fma(s2(VT3), xp, s2(VT2));
  f32x2 p45 = __builtin_elementwise_fma(s2(VT5), xp, s2(VT4));
  f32x2 qq  = __builtin_elementwise_fma(x2, p45, p23);
  f32x2 V   = __builtin_elementwise_fma(x2, qq, p01);
  f32x2 t2  = __builtin_elementwise_fma(xp, V, aaw);
  f32x2 e; e.x = EXP2F(t2.x); e.y = EXP2F(t2.y);
  return e;
}

// ---- prep kernel: 1 block, 384 threads; thread t = (layer l, comp k) ----
__global__ __launch_bounds__(384) void
prep_kernel(const float* __restrict__ mus,    // [L, D, K]
            const float* __restrict__ alphas, // [L, K]
            const float* __restrict__ wsv,    // [L]
            char* __restrict__ ws) {
  const int t = threadIdx.x;          // 0..383 == l*64+k
  const float* colp = mus + (t >> 6) * (DD * KK) + (t & 63);
  float v[DD];
  float ss = 0.0f;
#pragma unroll
  for (int d = 0; d < DD; ++d) { v[d] = colp[d * KK]; ss = fmaf(v[d], v[d], ss); }
  float inv = -0.5f / sqrtf(ss);      // normalize AND scale by -1/2 (exact scale)
  unsigned hw[8], lw[8];
#pragma unroll
  for (int i = 0; i < 8; ++i) {
    float a0 = v[2 * i] * inv;
    float a1 = v[2 * i + 1] * inv;
    ushort h0 = bf16_rne(a0), h1 = bf16_rne(a1);
    float hf0 = __uint_as_float((unsigned)h0 << 16);
    float hf1 = __uint_as_float((unsigned)h1 << 16);
    ushort l0 = bf16_rne(a0 - hf0), l1 = bf16_rne(a1 - hf1);
    hw[i] = (unsigned)h0 | ((unsigned)h1 << 16);
    lw[i] = (unsigned)l0 | ((unsigned)l1 << 16);
  }
  uint4* colq = (uint4*)(ws + WS_MU + t * 64);
  colq[0] = make_uint4(hw[0], hw[1], hw[2], hw[3]);
  colq[1] = make_uint4(hw[4], hw[5], hw[6], hw[7]);
  colq[2] = make_uint4(lw[0], lw[1], lw[2], lw[3]);
  colq[3] = make_uint4(lw[4], lw[5], lw[6], lw[7]);
  ((float*)(ws + WS_AV))[t] = fmaf(C_AA, alphas[t], -W0);
  if (t < LL) { float x = wsv[t]; ((float*)(ws + WS_WV))[t] = expf(-x * x); }
}

__global__ __launch_bounds__(TPB, 8) void
multiinf_kernel(const float* __restrict__ xs,
                const char* __restrict__ ws,
                float* __restrict__ out) {
  __shared__ __align__(16) char smem[LDS_BYTES];
  float* smc = (float*)(smem + SMC_OFF);
  char* sxu = smem;

  const int tid = threadIdx.x;
  const int w = tid >> 6;            // wave = layer
  const int lane = tid & 63;
  const int c = lane & 15;           // MFMA col: point-in-tile (comp-in-cb for A read)
  const int q = lane >> 4;           // quad
  const int h = q & 1;               // dim half for B (x) reads
  const int pbase = blockIdx.x * PTS_PER_BLOCK;

  // ---- A fragments (mu', loop-invariant) + per-comp constants from ws.
  //      24.5 KB total, L1/L2-resident after the first block on each CU.
  bf16x8 Am[4];
  f32x2 aaL[4], aaH[4];
#pragma unroll
  for (int cb = 0; cb < 4; ++cb) {
    Am[cb] = *(const bf16x8*)(ws + WS_MU + (w * 64 + cb * 16 + c) * 64 + q * 16);
    f32x4 a4 = *(const f32x4*)(ws + WS_AV + (w * 64 + cb * 16 + q * 4) * 4);
    aaL[cb].x = a4.x; aaL[cb].y = a4.y;
    aaH[cb].x = a4.z; aaH[cb].y = a4.w;
  }

  // ---- Stage x (bf16 hi/lo) into sxu ----
  if (tid < PTS_PER_BLOCK) {
    int gidx = pbase + tid;
    float xv[DD];
    if (gidx < NPOINTS) {
      const float4* x4 = (const float4*)(xs + (size_t)gidx * DD);
#pragma unroll
      for (int j = 0; j < 4; ++j) {
        float4 a = x4[j];
        xv[j * 4 + 0] = a.x; xv[j * 4 + 1] = a.y;
        xv[j * 4 + 2] = a.z; xv[j * 4 + 3] = a.w;
      }
    } else {
#pragma unroll
      for (int d = 0; d < DD; ++d) xv[d] = 0.0f;
    }
    unsigned hw[8], lw[8];
#pragma unroll
    for (int i = 0; i < 8; ++i) {
      ushort h0 = bf16_rne(xv[2 * i]);
      ushort h1 = bf16_rne(xv[2 * i + 1]);
      float hf0 = __uint_as_float((unsigned)h0 << 16);
      float hf1 = __uint_as_float((unsigned)h1 << 16);
      ushort l0 = bf16_rne(xv[2 * i] - hf0);
      ushort l1 = bf16_rne(xv[2 * i + 1] - hf1);
      hw[i] = (unsigned)h0 | ((unsigned)h1 << 16);
      lw[i] = (unsigned)l0 | ((unsigned)l1 << 16);
    }
    uint4* pq = (uint4*)(sxu + tid * 80);
    pq[0] = make_uint4(hw[0], hw[1], hw[2], hw[3]);
    pq[1] = make_uint4(hw[4], hw[5], hw[6], hw[7]);
    pq[2] = make_uint4(lw[0], lw[1], lw[2], lw[3]);
    pq[3] = make_uint4(lw[4], lw[5], lw[6], lw[7]);
  }

  __syncthreads();   // the ONLY pre-loop barrier

  // ---- Main loop: NTILES tiles of 16 points; lane owns point c of each tile
  float* smcw = smc + w * PTS_PER_BLOCK;
  const char* bbase = sxu + c * 80 + h * 16;   // +t*1280 selects the tile
  const f32x4 zero4 = {0.0f, 0.0f, 0.0f, 0.0f};
#pragma unroll
  for (int t = 0; t < NTILES; ++t) {
    bf16x8 Bh = *(const bf16x8*)(bbase + t * 1280);
    bf16x8 Bl = *(const bf16x8*)(bbase + t * 1280 + 32);
    f32x2 S01 = s2(0.0f), S23 = s2(0.0f);
#pragma unroll
    for (int cb = 0; cb < 4; ++cb) {
      f32x4 acc = __builtin_amdgcn_mfma_f32_16x16x32_bf16(Am[cb], Bh, zero4, 0, 0, 0);
      acc = __builtin_amdgcn_mfma_f32_16x16x32_bf16(Am[cb], Bl, acc, 0, 0, 0);
      f32x2 a01; a01.x = acc[0]; a01.y = acc[1];
      f32x2 a23; a23.x = acc[2]; a23.y = acc[3];
      S01 += term2(a01, aaL[cb]);
      S23 += term2(a23, aaH[cb]);
    }
    f32x2 Sf = S01 + S23;
    float St = Sf.x + Sf.y;
    St += __shfl_xor(St, 16, 64);
    St += __shfl_xor(St, 32, 64);
    if (lane < 16) smcw[t * 16 + c] = St;   // raw sum; log applied in epilogue
  }
  __syncthreads();

  // ---- Epilogue: recurrence + smooth-min, one thread per point ----
  if (tid < PTS_PER_BLOCK) {
    const float* swv = (const float*)(ws + WS_WV);
    float F = 0.0f;
#pragma unroll
    for (int l = 0; l < LL; ++l) {
      float wv = swv[l];
      float mc = C_GLN2 * LOG2F(smc[l * PTS_PER_BLOCK + tid]);  // gamma*ln(S)
      F = fmaf(wv, fmaxf(F, 0.0f), (1.0f - wv) * mc);
    }
    int idx = pbase + tid;
    if (idx < NPOINTS) {
      float e = EXP2F(F * C_AA);              // exp(-F/0.1)
      out[idx] = C_GLN2 * LOG2F(1.0f + e);    // 0.1 * ln(1 + e)
    }
  }
}

extern "C" void kernel_launch(void* const* d_in, const int* in_sizes, int n_in,
                              void* d_out, int out_size, void* d_ws, size_t ws_size,
                              hipStream_t stream) {
  const float* xs = (const float*)d_in[0];     // [N, D]
  const float* mus = (const float*)d_in[1];    // [L, D, K]
  const float* alphas = (const float*)d_in[2]; // [L, K]
  const float* wsv = (const float*)d_in[3];    // [L]
  float* out = (float*)d_out;
  char* ws = (char*)d_ws;
  (void)ws_size;

  prep_kernel<<<1, 384, 0, stream>>>(mus, alphas, wsv, ws);
  const int blocks = (NPOINTS + PTS_PER_BLOCK - 1) / PTS_PER_BLOCK;  // 1954
  multiinf_kernel<<<blocks, TPB, 0, stream>>>(xs, ws, out);
}

// Round 4
// 100.782 us; speedup vs baseline: 1.2025x; 1.2025x over previous
//
#include <hip/hip_runtime.h>
#include <math.h>

// Problem constants (reference: N=250000, D=16, L=6, K=64, gamma=0.1)
#define NPOINTS 250000
#define LL 6
#define DD 16
#define KK 64
#define TPB 384            // 6 waves; wave w handles layer w for the block's points
#define PTS_PER_BLOCK 128  // 1954 blocks: occupancy was grid-limited at 256
#define NTILES (PTS_PER_BLOCK / 16)

// LDS layout (byte offsets):
//  sxu:  point p at p*80,    [0, 10240)
//  smc:  SMC_OFF, 6*128*4 B  [10240, 13312)
#define SMC_OFF (PTS_PER_BLOCK * 80)
#define LDS_BYTES (SMC_OFF + LL * PTS_PER_BLOCK * 4)

// d_ws layout (bytes):
//  WS_MU: column (l*64+k) as 64 B = 32 B bf16-hi + 32 B bf16-lo, pre-scaled -1/2
//  WS_AV: av[l*64+k] = C_AA*alpha - W0
//  WS_WV: exp(-ws^2) per layer
#define WS_MU 0
#define WS_AV 24576
#define WS_WV 26112

typedef __attribute__((ext_vector_type(8))) short bf16x8;
typedef __attribute__((ext_vector_type(4))) float f32x4;
typedef __attribute__((ext_vector_type(2))) float f32x2;

#if __has_builtin(__builtin_amdgcn_exp2f)
#define EXP2F(x) __builtin_amdgcn_exp2f(x)
#else
#define EXP2F(x) exp2f(x)
#endif
#if __has_builtin(__builtin_amdgcn_logf)
#define LOG2F(x) __builtin_amdgcn_logf(x)
#else
#define LOG2F(x) log2f(x)
#endif

#define C_AA   (-14.426950408889634f)   // -10 * log2(e)
#define C_GLN2 (0.06931471805599453f)   // gamma * ln(2)

// Fused distance->log2 term: with mu pre-scaled by -1/2, MFMA emits x' = -ip/2
// and t2 = (aa - w0) + x'*Vt(x').  Vt = degree-5 poly (error budget: |err(F)|
// <= ~2.6e-4).  Estrin evaluation.
#define W0  17.797117f
#define VT0 (-45.300328f)
#define VT1 (-28.559404f)
#define VT2 (-27.844414f)
#define VT3 (-30.475230f)
#define VT4 (-36.246253f)
#define VT5 (-27.207285f)

__device__ __forceinline__ f32x2 s2(float v) { f32x2 r; r.x = v; r.y = v; return r; }

__device__ __forceinline__ ushort bf16_rne(float f) {
  unsigned u = __float_as_uint(f);
  unsigned r = u + 0x7FFFu + ((u >> 16) & 1u);
  return (ushort)(r >> 16);
}

// packed pair: exp2( (aa-w0) + xp*Vt(xp) ), xp = -ip/2 from MFMA.  Estrin:
// Vt = P01 + xp^2*(P23 + xp^2*P45), Pij = VTi + VTj*xp.
__device__ __forceinline__ f32x2 term2(f32x2 xp, f32x2 aaw) {
  f32x2 x2  = xp * xp;
  f32x2 p01 = __builtin_elementwise_fma(s2(VT1), xp, s2(VT0));
  f32x2 p23 = __builtin_elementwise_fma(s2(VT3), xp, s2(VT2));
  f32x2 p45 = __builtin_elementwise_fma(s2(VT5), xp, s2(VT4));
  f32x2 qq  = __builtin_elementwise_fma(x2, p45, p23);
  f32x2 V   = __builtin_elementwise_fma(x2, qq, p01);
  f32x2 t2  = __builtin_elementwise_fma(xp, V, aaw);
  f32x2 e; e.x = EXP2F(t2.x); e.y = EXP2F(t2.y);
  return e;
}

// ---- prep kernel: 1 block, 384 threads; thread t = (layer l, comp k) ----
__global__ __launch_bounds__(384) void
prep_kernel(const float* __restrict__ mus,    // [L, D, K]
            const float* __restrict__ alphas, // [L, K]
            const float* __restrict__ wsv,    // [L]
            char* __restrict__ ws) {
  const int t = threadIdx.x;          // 0..383 == l*64+k
  const float* colp = mus + (t >> 6) * (DD * KK) + (t & 63);
  float v[DD];
  float ss = 0.0f;
#pragma unroll
  for (int d = 0; d < DD; ++d) { v[d] = colp[d * KK]; ss = fmaf(v[d], v[d], ss); }
  float inv = -0.5f / sqrtf(ss);      // normalize AND scale by -1/2 (exact scale)
  unsigned hw[8], lw[8];
#pragma unroll
  for (int i = 0; i < 8; ++i) {
    float a0 = v[2 * i] * inv;
    float a1 = v[2 * i + 1] * inv;
    ushort h0 = bf16_rne(a0), h1 = bf16_rne(a1);
    float hf0 = __uint_as_float((unsigned)h0 << 16);
    float hf1 = __uint_as_float((unsigned)h1 << 16);
    ushort l0 = bf16_rne(a0 - hf0), l1 = bf16_rne(a1 - hf1);
    hw[i] = (unsigned)h0 | ((unsigned)h1 << 16);
    lw[i] = (unsigned)l0 | ((unsigned)l1 << 16);
  }
  uint4* colq = (uint4*)(ws + WS_MU + t * 64);
  colq[0] = make_uint4(hw[0], hw[1], hw[2], hw[3]);
  colq[1] = make_uint4(hw[4], hw[5], hw[6], hw[7]);
  colq[2] = make_uint4(lw[0], lw[1], lw[2], lw[3]);
  colq[3] = make_uint4(lw[4], lw[5], lw[6], lw[7]);
  ((float*)(ws + WS_AV))[t] = fmaf(C_AA, alphas[t], -W0);
  if (t < LL) { float x = wsv[t]; ((float*)(ws + WS_WV))[t] = expf(-x * x); }
}

// R16: launch_bounds back to (TPB,4) — R3's (TPB,8) forced the allocator to
// 32 VGPRs and spilled ~15 dwords/thread to scratch (WRITE_SIZE 45 MB).
// 44 VGPR (R1-measured) <= 64 keeps the 8-waves/EU HW cap anyway.
__global__ __launch_bounds__(TPB, 4) void
multiinf_kernel(const float* __restrict__ xs,
                const char* __restrict__ ws,
                float* __restrict__ out) {
  __shared__ __align__(16) char smem[LDS_BYTES];
  float* smc = (float*)(smem + SMC_OFF);
  char* sxu = smem;

  const int tid = threadIdx.x;
  const int w = tid >> 6;            // wave = layer
  const int lane = tid & 63;
  const int c = lane & 15;           // MFMA col: point-in-tile (comp-in-cb for A read)
  const int q = lane >> 4;           // quad
  const int h = q & 1;               // dim half for B (x) reads
  const int pbase = blockIdx.x * PTS_PER_BLOCK;

  // ---- A fragments (mu', loop-invariant) + per-comp constants from ws.
  //      24.5 KB total, L1/L2-resident after the first block on each CU.
  bf16x8 Am[4];
  f32x2 aaL[4], aaH[4];
#pragma unroll
  for (int cb = 0; cb < 4; ++cb) {
    Am[cb] = *(const bf16x8*)(ws + WS_MU + (w * 64 + cb * 16 + c) * 64 + q * 16);
    f32x4 a4 = *(const f32x4*)(ws + WS_AV + (w * 64 + cb * 16 + q * 4) * 4);
    aaL[cb].x = a4.x; aaL[cb].y = a4.y;
    aaH[cb].x = a4.z; aaH[cb].y = a4.w;
  }

  // ---- Stage x (bf16 hi/lo) into sxu ----
  if (tid < PTS_PER_BLOCK) {
    int gidx = pbase + tid;
    float xv[DD];
    if (gidx < NPOINTS) {
      const float4* x4 = (const float4*)(xs + (size_t)gidx * DD);
#pragma unroll
      for (int j = 0; j < 4; ++j) {
        float4 a = x4[j];
        xv[j * 4 + 0] = a.x; xv[j * 4 + 1] = a.y;
        xv[j * 4 + 2] = a.z; xv[j * 4 + 3] = a.w;
      }
    } else {
#pragma unroll
      for (int d = 0; d < DD; ++d) xv[d] = 0.0f;
    }
    unsigned hw[8], lw[8];
#pragma unroll
    for (int i = 0; i < 8; ++i) {
      ushort h0 = bf16_rne(xv[2 * i]);
      ushort h1 = bf16_rne(xv[2 * i + 1]);
      float hf0 = __uint_as_float((unsigned)h0 << 16);
      float hf1 = __uint_as_float((unsigned)h1 << 16);
      ushort l0 = bf16_rne(xv[2 * i] - hf0);
      ushort l1 = bf16_rne(xv[2 * i + 1] - hf1);
      hw[i] = (unsigned)h0 | ((unsigned)h1 << 16);
      lw[i] = (unsigned)l0 | ((unsigned)l1 << 16);
    }
    uint4* pq = (uint4*)(sxu + tid * 80);
    pq[0] = make_uint4(hw[0], hw[1], hw[2], hw[3]);
    pq[1] = make_uint4(hw[4], hw[5], hw[6], hw[7]);
    pq[2] = make_uint4(lw[0], lw[1], lw[2], lw[3]);
    pq[3] = make_uint4(lw[4], lw[5], lw[6], lw[7]);
  }

  __syncthreads();   // the ONLY pre-loop barrier

  // ---- Main loop: NTILES tiles of 16 points; lane owns point c of each tile
  float* smcw = smc + w * PTS_PER_BLOCK;
  const char* bbase = sxu + c * 80 + h * 16;   // +t*1280 selects the tile
  const f32x4 zero4 = {0.0f, 0.0f, 0.0f, 0.0f};
#pragma unroll
  for (int t = 0; t < NTILES; ++t) {
    bf16x8 Bh = *(const bf16x8*)(bbase + t * 1280);
    bf16x8 Bl = *(const bf16x8*)(bbase + t * 1280 + 32);
    f32x2 S01 = s2(0.0f), S23 = s2(0.0f);
#pragma unroll
    for (int cb = 0; cb < 4; ++cb) {
      f32x4 acc = __builtin_amdgcn_mfma_f32_16x16x32_bf16(Am[cb], Bh, zero4, 0, 0, 0);
      acc = __builtin_amdgcn_mfma_f32_16x16x32_bf16(Am[cb], Bl, acc, 0, 0, 0);
      f32x2 a01; a01.x = acc[0]; a01.y = acc[1];
      f32x2 a23; a23.x = acc[2]; a23.y = acc[3];
      S01 += term2(a01, aaL[cb]);
      S23 += term2(a23, aaH[cb]);
    }
    f32x2 Sf = S01 + S23;
    float St = Sf.x + Sf.y;
    St += __shfl_xor(St, 16, 64);
    St += __shfl_xor(St, 32, 64);
    if (lane < 16) smcw[t * 16 + c] = St;   // raw sum; log applied in epilogue
  }
  __syncthreads();

  // ---- Epilogue: recurrence + smooth-min, one thread per point ----
  if (tid < PTS_PER_BLOCK) {
    const float* swv = (const float*)(ws + WS_WV);
    float F = 0.0f;
#pragma unroll
    for (int l = 0; l < LL; ++l) {
      float wv = swv[l];
      float mc = C_GLN2 * LOG2F(smc[l * PTS_PER_BLOCK + tid]);  // gamma*ln(S)
      F = fmaf(wv, fmaxf(F, 0.0f), (1.0f - wv) * mc);
    }
    int idx = pbase + tid;
    if (idx < NPOINTS) {
      float e = EXP2F(F * C_AA);              // exp(-F/0.1)
      out[idx] = C_GLN2 * LOG2F(1.0f + e);    // 0.1 * ln(1 + e)
    }
  }
}

extern "C" void kernel_launch(void* const* d_in, const int* in_sizes, int n_in,
                              void* d_out, int out_size, void* d_ws, size_t ws_size,
                              hipStream_t stream) {
  const float* xs = (const float*)d_in[0];     // [N, D]
  const float* mus = (const float*)d_in[1];    // [L, D, K]
  const float* alphas = (const float*)d_in[2]; // [L, K]
  const float* wsv = (const float*)d_in[3];    // [L]
  float* out = (float*)d_out;
  char* ws = (char*)d_ws;
  (void)ws_size;

  prep_kernel<<<1, 384, 0, stream>>>(mus, alphas, wsv, ws);
  const int blocks = (NPOINTS + PTS_PER_BLOCK - 1) / PTS_PER_BLOCK;  // 1954
  multiinf_kernel<<<blocks, TPB, 0, stream>>>(xs, ws, out);
}